// Round 1
// baseline (170.151 us; speedup 1.0000x reference)
//
#include <hip/hip_runtime.h>
#include <cstddef>

// Problem constants
constexpr int BH = 32;    // batch*heads
constexpr int N  = 8192;  // sequence
constexpr int D  = 64;    // dim
constexpr int BK = 64;    // bucket size
constexpr int NB = 128;   // N / BK buckets
constexpr int NC = 129;   // NB + 1 (padded sk)

// ---------------------------------------------------------------------------
// Kernel A: per (b, bucket j) compute
//   qsum[b,j,d]   = sum_{t in bucket} q
//   ksum[b,j,d]   = sum_{t in bucket} k
//   kw[b,j,d]     = sum_{t in bucket} k * tailw(j,t),  tailw = suffix harmonic
//   qfirst[b,j,d] = q[b, j*64, d]
//   W[j]          = tailw(j, 0)   (bucket-window harmonic sum, b-independent)
// Reads q,k exactly once, float4-coalesced.
// ---------------------------------------------------------------------------
__global__ __launch_bounds__(256) void kA(const float* __restrict__ q,
                                          const float* __restrict__ k,
                                          float* __restrict__ qsum,
                                          float* __restrict__ ksum,
                                          float* __restrict__ kw,
                                          float* __restrict__ qfirst,
                                          float* __restrict__ W) {
  const int j   = blockIdx.x;
  const int b   = blockIdx.y;
  const int tid = threadIdx.x;
  const int base = j * BK;

  __shared__ float winv[BK];
  __shared__ float tailw[BK];
  __shared__ float red[3][16][D];   // 12 KB

  if (tid < BK) winv[tid] = 1.0f / (float)(base + tid + 1);
  __syncthreads();
  if (tid < BK) {
    float s = 0.0f;
    for (int u = BK - 1; u >= tid; --u) s += winv[u];
    tailw[tid] = s;
  }
  __syncthreads();

  const float4* q4 = (const float4*)(q + ((size_t)b * N + base) * D);
  const float4* k4 = (const float4*)(k + ((size_t)b * N + base) * D);
  const int f  = tid & 15;   // float4 column (d = 4f..4f+3)
  const int r0 = tid >> 4;   // 0..15

  float aq[4] = {0,0,0,0}, ak[4] = {0,0,0,0}, aw[4] = {0,0,0,0};
  float qf[4] = {0,0,0,0};

#pragma unroll
  for (int p = 0; p < 4; ++p) {
    const int row = p * 16 + r0;
    const float4 qv = q4[row * 16 + f];
    const float4 kv = k4[row * 16 + f];
    const float tw = tailw[row];
    aq[0] += qv.x; aq[1] += qv.y; aq[2] += qv.z; aq[3] += qv.w;
    ak[0] += kv.x; ak[1] += kv.y; ak[2] += kv.z; ak[3] += kv.w;
    aw[0] += kv.x * tw; aw[1] += kv.y * tw; aw[2] += kv.z * tw; aw[3] += kv.w * tw;
    if (p == 0 && r0 == 0) { qf[0] = qv.x; qf[1] = qv.y; qf[2] = qv.z; qf[3] = qv.w; }
  }

#pragma unroll
  for (int c = 0; c < 4; ++c) {
    red[0][r0][4*f + c] = aq[c];
    red[1][r0][4*f + c] = ak[c];
    red[2][r0][4*f + c] = aw[c];
  }
  __syncthreads();

  const size_t ob = ((size_t)b * NB + j) * D;
  if (tid < D) {
    float sq_ = 0.f, sk_ = 0.f, sw_ = 0.f;
#pragma unroll
    for (int r = 0; r < 16; ++r) {
      sq_ += red[0][r][tid];
      sk_ += red[1][r][tid];
      sw_ += red[2][r][tid];
    }
    qsum[ob + tid] = sq_;
    ksum[ob + tid] = sk_;
    kw[ob + tid]   = sw_;
  }
  if (r0 == 0) {  // tid < 16, f == tid : holds row-0 q values
    ((float4*)(qfirst + ob))[f] = make_float4(qf[0], qf[1], qf[2], qf[3]);
  }
  if (tid == 0 && b == 0) W[j] = tailw[0];
}

// ---------------------------------------------------------------------------
// Kernel B: per b, prefix-scan buckets.
//   sq[b,i,d]     = (prefQ_excl + qfirst) / (i*64 + 1)
//   skp[b,0,d]    = 0 ; skp[b,j+1,d] = prefK_excl * W[j] + kw[b,j,d]
// 4 j-groups of 32 each to cut the serial chain.
// ---------------------------------------------------------------------------
__global__ __launch_bounds__(256) void kB(const float* __restrict__ qsum,
                                          const float* __restrict__ ksum,
                                          const float* __restrict__ kw,
                                          const float* __restrict__ qfirst,
                                          const float* __restrict__ W,
                                          float* __restrict__ sq,
                                          float* __restrict__ skp) {
  const int b   = blockIdx.x;
  const int tid = threadIdx.x;
  const int d   = tid & 63;
  const int jg  = tid >> 6;  // 0..3

  __shared__ float qtot[4][D], ktot[4][D];

  const float* qs = qsum + (size_t)b * NB * D;
  const float* ks = ksum + (size_t)b * NB * D;

  float qt = 0.f, kt = 0.f;
  for (int jj = 0; jj < 32; ++jj) {
    const int j = jg * 32 + jj;
    qt += qs[j * D + d];
    kt += ks[j * D + d];
  }
  qtot[jg][d] = qt;
  ktot[jg][d] = kt;
  __syncthreads();

  float qpre = 0.f, kpre = 0.f;
  for (int g = 0; g < jg; ++g) { qpre += qtot[g][d]; kpre += ktot[g][d]; }

  if (tid < D) skp[(size_t)b * NC * D + tid] = 0.0f;  // pad row j=0

  for (int jj = 0; jj < 32; ++jj) {
    const int j = jg * 32 + jj;
    const size_t o = ((size_t)b * NB + j) * D + d;
    sq[o] = (qpre + qfirst[o]) / (float)(j * BK + 1);
    skp[((size_t)b * NC + j + 1) * D + d] = kpre * W[j] + kw[o];
    qpre += qs[j * D + d];
    kpre += ks[j * D + d];
  }
}

// ---------------------------------------------------------------------------
// Kernel C: one (b,i) row of R. thread j computes dot(sq[b,i], skp[b,j])/8,
// block softmax over valid j<=i, output keeps only j<i.
// ---------------------------------------------------------------------------
__global__ __launch_bounds__(256) void kC(const float* __restrict__ sq,
                                          const float* __restrict__ skp,
                                          float* __restrict__ out) {
  const int i   = blockIdx.x;
  const int b   = blockIdx.y;
  const int tid = threadIdx.x;

  __shared__ float srow[D];
  __shared__ float rbuf[256];

  if (tid < D) srow[tid] = sq[((size_t)b * NB + i) * D + tid];
  __syncthreads();

  const bool valid = (tid <= i);  // i <= 127 so valid implies tid < NC
  float dot = 0.0f;
  if (valid) {
    const float4* kr = (const float4*)(skp + ((size_t)b * NC + tid) * D);
    const float4* sr = (const float4*)srow;
#pragma unroll
    for (int f = 0; f < 16; ++f) {
      const float4 a = sr[f];
      const float4 c = kr[f];
      dot += a.x * c.x + a.y * c.y + a.z * c.z + a.w * c.w;
    }
    dot *= 0.125f;  // DIM^-0.5
  }

  rbuf[tid] = valid ? dot : -3.402823466e38f;
  __syncthreads();
  for (int s = 128; s > 0; s >>= 1) {
    if (tid < s) rbuf[tid] = fmaxf(rbuf[tid], rbuf[tid + s]);
    __syncthreads();
  }
  const float mx = rbuf[0];
  __syncthreads();

  const float e = valid ? expf(dot - mx) : 0.0f;
  rbuf[tid] = e;
  __syncthreads();
  for (int s = 128; s > 0; s >>= 1) {
    if (tid < s) rbuf[tid] += rbuf[tid + s];
    __syncthreads();
  }
  const float denom = rbuf[0];

  if (tid < NC) {
    out[((size_t)b * NB + i) * NC + tid] = (tid < i) ? (e / denom) : 0.0f;
  }
}

// ---------------------------------------------------------------------------
extern "C" void kernel_launch(void* const* d_in, const int* in_sizes, int n_in,
                              void* d_out, int out_size, void* d_ws, size_t ws_size,
                              hipStream_t stream) {
  const float* q = (const float*)d_in[0];
  const float* k = (const float*)d_in[1];
  float* out = (float*)d_out;

  float* ws     = (float*)d_ws;
  float* qsum   = ws;                      // BH*NB*D
  float* ksum   = qsum   + (size_t)BH * NB * D;
  float* kw     = ksum   + (size_t)BH * NB * D;
  float* qfirst = kw     + (size_t)BH * NB * D;
  float* sq     = qfirst + (size_t)BH * NB * D;
  float* skp    = sq     + (size_t)BH * NB * D;  // BH*NC*D
  float* W      = skp    + (size_t)BH * NC * D;  // NB

  kA<<<dim3(NB, BH), 256, 0, stream>>>(q, k, qsum, ksum, kw, qfirst, W);
  kB<<<dim3(BH), 256, 0, stream>>>(qsum, ksum, kw, qfirst, W, sq, skp);
  kC<<<dim3(NB, BH), 256, 0, stream>>>(sq, skp, out);
}